// Round 1
// baseline (244.970 us; speedup 1.0000x reference)
//
#include <hip/hip_runtime.h>
#include <hip/hip_bf16.h>
#include <stdint.h>

typedef __attribute__((ext_vector_type(8))) short short8;
typedef __attribute__((ext_vector_type(4))) float f32x4;
typedef __attribute__((ext_vector_type(4))) float float4v;
typedef __attribute__((ext_vector_type(4))) int int4v;

#define IN_F 2048
#define OUT_F 8192
#define M_DIM 4096   // BATCH * SEQ
#define BM 128
#define BN 128
#define BK 32

__device__ __constant__ float c_lut[15] = {
    -1.0f, -0.5f, -0.333333f, -0.2f, -0.142857f, -0.090909f, -0.076923f,
    0.0f, 0.076923f, 0.090909f, 0.142857f, 0.2f, 0.333333f, 0.5f, 1.0f};

// fp32 -> bf16 round-to-nearest-even
__device__ inline ushort f2bf(float f) {
    union { float f; uint32_t u; } v; v.f = f;
    uint32_t u = v.u;
    u += 0x7fffu + ((u >> 16) & 1u);
    return (ushort)(u >> 16);
}

// global -> LDS direct load, 16B per lane. LDS dest must be linear
// (wave-uniform base + lane*16). Cast via integer to reach addrspace(3).
__device__ inline void gload_lds16(const void* g, void* l) {
    __builtin_amdgcn_global_load_lds(
        (const __attribute__((address_space(1))) void*)(uintptr_t)g,
        (__attribute__((address_space(3))) void*)(uint32_t)(uintptr_t)l,
        16, 0, 0);
}

// ---------------- dequant: grid_indices[int32] -> w_bf16 [OUT_F][IN_F] ----------------
__global__ __launch_bounds__(256) void dequant_w(const int* __restrict__ gi,
                                                 const float* __restrict__ scale_p,
                                                 ushort* __restrict__ w) {
    __shared__ float lut_s[16];
    if (threadIdx.x < 16) {
        float s = scale_p[0];
        lut_s[threadIdx.x] = (threadIdx.x < 15 ? c_lut[threadIdx.x] : 0.0f) * s;
    }
    __syncthreads();
    size_t t = (size_t)blockIdx.x * 256 + threadIdx.x;   // 8 elems per thread
    const int4v* src = (const int4v*)gi;
    int4v v0 = src[t * 2];
    int4v v1 = src[t * 2 + 1];
    short8 o;
    o[0] = (short)f2bf(lut_s[v0.x]);
    o[1] = (short)f2bf(lut_s[v0.y]);
    o[2] = (short)f2bf(lut_s[v0.z]);
    o[3] = (short)f2bf(lut_s[v0.w]);
    o[4] = (short)f2bf(lut_s[v1.x]);
    o[5] = (short)f2bf(lut_s[v1.y]);
    o[6] = (short)f2bf(lut_s[v1.z]);
    o[7] = (short)f2bf(lut_s[v1.w]);
    ((short8*)w)[t] = o;
}

// ---------------- x fp32 -> bf16 [M_DIM][IN_F] ----------------
__global__ __launch_bounds__(256) void xconv(const float* __restrict__ x,
                                             ushort* __restrict__ xb) {
    size_t t = (size_t)blockIdx.x * 256 + threadIdx.x;   // 8 elems per thread
    const float4v* src = (const float4v*)x;
    float4v v0 = src[t * 2];
    float4v v1 = src[t * 2 + 1];
    short8 o;
    o[0] = (short)f2bf(v0.x);
    o[1] = (short)f2bf(v0.y);
    o[2] = (short)f2bf(v0.z);
    o[3] = (short)f2bf(v0.w);
    o[4] = (short)f2bf(v1.x);
    o[5] = (short)f2bf(v1.y);
    o[6] = (short)f2bf(v1.z);
    o[7] = (short)f2bf(v1.w);
    ((short8*)xb)[t] = o;
}

// ---------------- GEMM: C[M][N] = A[M][K] * B[N][K]^T  (bf16 in, fp32 out) ----------------
// m97 structure: 128x128 tile, BK=32, 4 waves (2x2), 4x4 16x16 fragments per wave,
// width-16 global_load_lds staging, 2-barrier K-loop.
__global__ __launch_bounds__(256) void gemm_bf16(const ushort* __restrict__ A,
                                                 const ushort* __restrict__ B,
                                                 float* __restrict__ C) {
    __shared__ ushort As[BM * BK];   // 8 KB
    __shared__ ushort Bs[BN * BK];   // 8 KB

    const int tid  = threadIdx.x;
    const int wid  = tid >> 6;
    const int lane = tid & 63;
    const int wr = wid >> 1, wc = wid & 1;   // wave sub-tile (64x64) coords
    const int g = lane >> 4;                 // k-group 0..3
    const int r = lane & 15;                 // row/col within fragment

    // XCD-aware bijective swizzle (gridDim.x = 2048, divisible by 8)
    const int nwg = gridDim.x;
    const int bid = blockIdx.x;
    const int swz = (bid & 7) * (nwg >> 3) + (bid >> 3);
    const int nbn = OUT_F / BN;              // 64
    const int bm = (swz / nbn) * BM;
    const int bn = (swz % nbn) * BN;

    // staging: thread t covers tile row (t>>2) (+64 for 2nd issue), cols (t&3)*8..+7
    const int srow = tid >> 2;
    const int scol = (tid & 3) * 8;
    const ushort* a_src = A + (size_t)(bm + srow) * IN_F + scol;
    const ushort* b_src = B + (size_t)(bn + srow) * IN_F + scol;
    ushort* as_dst = As + tid * 8;           // byte offset tid*16, linear lane order
    ushort* bs_dst = Bs + tid * 8;

    f32x4 acc[4][4] = {};

    for (int kt = 0; kt < IN_F; kt += BK) {
        gload_lds16(a_src,              as_dst);
        gload_lds16(a_src + 64 * IN_F,  as_dst + 2048);
        gload_lds16(b_src,              bs_dst);
        gload_lds16(b_src + 64 * IN_F,  bs_dst + 2048);
        a_src += BK;
        b_src += BK;
        __syncthreads();   // drains vmcnt -> staged data visible

        short8 af[4], bf[4];
#pragma unroll
        for (int i = 0; i < 4; ++i)
            af[i] = *(const short8*)(As + (wr * 64 + i * 16 + r) * BK + g * 8);
#pragma unroll
        for (int i = 0; i < 4; ++i)
            bf[i] = *(const short8*)(Bs + (wc * 64 + i * 16 + r) * BK + g * 8);

#pragma unroll
        for (int mi = 0; mi < 4; ++mi)
#pragma unroll
            for (int ni = 0; ni < 4; ++ni)
                acc[mi][ni] = __builtin_amdgcn_mfma_f32_16x16x32_bf16(
                    af[mi], bf[ni], acc[mi][ni], 0, 0, 0);

        __syncthreads();   // all waves done reading before next stage overwrites
    }

    // epilogue: C/D layout col = lane&15, row = (lane>>4)*4 + reg   [verified m89/m91]
#pragma unroll
    for (int mi = 0; mi < 4; ++mi) {
#pragma unroll
        for (int ni = 0; ni < 4; ++ni) {
            const int row0 = bm + wr * 64 + mi * 16 + g * 4;
            const int col  = bn + wc * 64 + ni * 16 + r;
#pragma unroll
            for (int j = 0; j < 4; ++j)
                C[(size_t)(row0 + j) * OUT_F + col] = acc[mi][ni][j];
        }
    }
}

extern "C" void kernel_launch(void* const* d_in, const int* in_sizes, int n_in,
                              void* d_out, int out_size, void* d_ws, size_t ws_size,
                              hipStream_t stream) {
    const float* x     = (const float*)d_in[0];
    const int*   gi    = (const int*)d_in[1];
    const float* scale = (const float*)d_in[2];
    float* out = (float*)d_out;

    ushort* wbf = (ushort*)d_ws;                          // 32 MB
    ushort* xbf = (ushort*)d_ws + (size_t)OUT_F * IN_F;   // +16 MB

    // W dequant: 16.78M elems / 8 per thread / 256 per block
    dequant_w<<<8192, 256, 0, stream>>>(gi, scale, wbf);
    // x convert: 8.39M elems / 8 per thread / 256 per block
    xconv<<<4096, 256, 0, stream>>>(x, xbf);
    // GEMM: 32 x 64 tiles
    gemm_bf16<<<(M_DIM / BM) * (OUT_F / BN), 256, 0, stream>>>(xbf, wbf, out);
}

// Round 2
// 169.813 us; speedup vs baseline: 1.4426x; 1.4426x over previous
//
#include <hip/hip_runtime.h>
#include <hip/hip_bf16.h>
#include <stdint.h>

typedef __attribute__((ext_vector_type(8))) short short8;
typedef __attribute__((ext_vector_type(4))) float f32x4;
typedef __attribute__((ext_vector_type(4))) float float4v;
typedef __attribute__((ext_vector_type(4))) int int4v;

#define IN_F 2048
#define OUT_F 8192
#define M_DIM 4096   // BATCH * SEQ
#define NT (IN_F / 64)   // 32 K-tiles of BK=64

__device__ __constant__ float c_lut[15] = {
    -1.0f, -0.5f, -0.333333f, -0.2f, -0.142857f, -0.090909f, -0.076923f,
    0.0f, 0.076923f, 0.090909f, 0.142857f, 0.2f, 0.333333f, 0.5f, 1.0f};

// fp32 -> bf16 round-to-nearest-even
__device__ inline ushort f2bf(float f) {
    union { float f; uint32_t u; } v; v.f = f;
    uint32_t u = v.u;
    u += 0x7fffu + ((u >> 16) & 1u);
    return (ushort)(u >> 16);
}

// global -> LDS direct load, 16B per lane; LDS dest linear (base + lane*16).
__device__ inline void gload_lds16(const void* g, void* l) {
    __builtin_amdgcn_global_load_lds(
        (const __attribute__((address_space(1))) void*)(uintptr_t)g,
        (__attribute__((address_space(3))) void*)(uint32_t)(uintptr_t)l,
        16, 0, 0);
}

// ---------------- dequant: grid_indices[int32] -> w_bf16 [OUT_F][IN_F] ----------------
__global__ __launch_bounds__(256) void dequant_w(const int* __restrict__ gi,
                                                 const float* __restrict__ scale_p,
                                                 ushort* __restrict__ w) {
    __shared__ float lut_s[16];
    if (threadIdx.x < 16) {
        float s = scale_p[0];
        lut_s[threadIdx.x] = (threadIdx.x < 15 ? c_lut[threadIdx.x] : 0.0f) * s;
    }
    __syncthreads();
    size_t t = (size_t)blockIdx.x * 256 + threadIdx.x;   // 8 elems per thread
    const int4v* src = (const int4v*)gi;
    int4v v0 = src[t * 2];
    int4v v1 = src[t * 2 + 1];
    short8 o;
    o[0] = (short)f2bf(lut_s[v0.x]);
    o[1] = (short)f2bf(lut_s[v0.y]);
    o[2] = (short)f2bf(lut_s[v0.z]);
    o[3] = (short)f2bf(lut_s[v0.w]);
    o[4] = (short)f2bf(lut_s[v1.x]);
    o[5] = (short)f2bf(lut_s[v1.y]);
    o[6] = (short)f2bf(lut_s[v1.z]);
    o[7] = (short)f2bf(lut_s[v1.w]);
    ((short8*)w)[t] = o;
}

// ---------------- x fp32 -> bf16 [M_DIM][IN_F] ----------------
__global__ __launch_bounds__(256) void xconv(const float* __restrict__ x,
                                             ushort* __restrict__ xb) {
    size_t t = (size_t)blockIdx.x * 256 + threadIdx.x;   // 8 elems per thread
    const float4v* src = (const float4v*)x;
    float4v v0 = src[t * 2];
    float4v v1 = src[t * 2 + 1];
    short8 o;
    o[0] = (short)f2bf(v0.x);
    o[1] = (short)f2bf(v0.y);
    o[2] = (short)f2bf(v0.z);
    o[3] = (short)f2bf(v0.w);
    o[4] = (short)f2bf(v1.x);
    o[5] = (short)f2bf(v1.y);
    o[6] = (short)f2bf(v1.z);
    o[7] = (short)f2bf(v1.w);
    ((short8*)xb)[t] = o;
}

// ---------------- GEMM: C[M][N] = A[M][K] * B[N][K]^T (bf16 in, fp32 out) ----------------
// 256x256 tile, BK=64, 8 waves (2M x 4N), 4 phases/K-tile (one C-quadrant each,
// 16 MFMA), double-buffered 128 KiB LDS, XOR read-swizzle (inverse-swizzled
// global source, linear global_load_lds dest), raw s_barrier + single vmcnt(0)
// per K-tile (staging front-loaded 2+ phases earlier), setprio around MFMA.
__global__ __launch_bounds__(512, 2) void gemm8p(const ushort* __restrict__ A,
                                                 const ushort* __restrict__ Bm,
                                                 float* __restrict__ C) {
    __shared__ ushort lds[2][2][256][64];   // [dbuf][A/B][row][col] = 128 KiB

    const int tid  = threadIdx.x;
    const int lane = tid & 63;
    const int wid  = tid >> 6;
    const int wm = wid >> 2;   // 0..1 : wave's 128-row band
    const int wn = wid & 3;    // 0..3 : wave's 64-col band
    const int g = lane >> 4;   // 0..3
    const int r = lane & 15;

    const int bm = (int)(blockIdx.x & 15) * 256;   // 16 M-tiles (fast) — shares B panel
    const int bn = (int)(blockIdx.x >> 4) * 256;   // 32 N-tiles

    // Staging: issue covers 64 rows; thread t -> row t>>3, 16B-slot (t&7)^((t>>3)&7)
    // (inverse-swizzled SOURCE so the linear LDS write realizes the read swizzle).
    const int srow  = tid >> 3;
    const int sslot = (tid & 7) ^ (srow & 7);
    const ushort* a_src = A  + (size_t)(bm + srow) * IN_F + sslot * 8;
    const ushort* b_src = Bm + (size_t)(bn + srow) * IN_F + sslot * 8;

#define STAGE4(cbuf, opi, srcp, kofs)                                   \
    do {                                                                \
        ushort* _d = &lds[cbuf][opi][0][0] + tid * 8;                   \
        const ushort* _s = (srcp) + (kofs);                             \
        gload_lds16(_s,                _d);                             \
        gload_lds16(_s +  64 * IN_F,   _d + 4096);                      \
        gload_lds16(_s + 128 * IN_F,   _d + 8192);                      \
        gload_lds16(_s + 192 * IN_F,   _d + 12288);                     \
    } while (0)

    f32x4 acc[8][4] = {};

    // prologue: stage K-tile 0 into buffer 0
    STAGE4(0, 0, a_src, 0);
    STAGE4(0, 1, b_src, 0);
    asm volatile("s_waitcnt vmcnt(0)" ::: "memory");
    __builtin_amdgcn_s_barrier();

    for (int t = 0; t < NT; ++t) {
        const int c = t & 1;
        const bool more = (t + 1 < NT);
#pragma unroll
        for (int q = 0; q < 4; ++q) {
            const int qm = q >> 1, qn = q & 1;   // C-quadrant of this wave's 128x64
            short8 af[4][2], bfv[2][2];
#pragma unroll
            for (int f = 0; f < 4; ++f) {
                const int row = wm * 128 + qm * 64 + f * 16 + r;
#pragma unroll
                for (int ks = 0; ks < 2; ++ks) {
                    const int slot = (ks * 4 + g) ^ (r & 7);
                    af[f][ks] = *(const short8*)&lds[c][0][row][slot * 8];
                }
            }
#pragma unroll
            for (int f = 0; f < 2; ++f) {
                const int row = wn * 64 + qn * 32 + f * 16 + r;
#pragma unroll
                for (int ks = 0; ks < 2; ++ks) {
                    const int slot = (ks * 4 + g) ^ (r & 7);
                    bfv[f][ks] = *(const short8*)&lds[c][1][row][slot * 8];
                }
            }
            // front-loaded prefetch of K-tile t+1 into the other buffer
            if (q == 0 && more) STAGE4(c ^ 1, 0, a_src, (t + 1) * 64);
            if (q == 1 && more) STAGE4(c ^ 1, 1, b_src, (t + 1) * 64);

            __builtin_amdgcn_s_barrier();
            __builtin_amdgcn_s_setprio(1);
#pragma unroll
            for (int f = 0; f < 4; ++f)
#pragma unroll
                for (int f2 = 0; f2 < 2; ++f2)
#pragma unroll
                    for (int ks = 0; ks < 2; ++ks)
                        acc[qm * 4 + f][qn * 2 + f2] =
                            __builtin_amdgcn_mfma_f32_16x16x32_bf16(
                                af[f][ks], bfv[f2][ks],
                                acc[qm * 4 + f][qn * 2 + f2], 0, 0, 0);
            __builtin_amdgcn_s_setprio(0);
            if (q == 3) asm volatile("s_waitcnt vmcnt(0)" ::: "memory");  // loads >=2 phases old
            __builtin_amdgcn_s_barrier();
        }
    }

    // epilogue: C/D layout col = lane&15, row = (lane>>4)*4 + reg  [verified m89/m91]
    const int crow0 = bm + wm * 128 + g * 4;
    const int ccol0 = bn + wn * 64 + r;
#pragma unroll
    for (int mi = 0; mi < 8; ++mi)
#pragma unroll
        for (int ni = 0; ni < 4; ++ni)
#pragma unroll
            for (int j = 0; j < 4; ++j)
                C[(size_t)(crow0 + mi * 16 + j) * OUT_F + ccol0 + ni * 16] = acc[mi][ni][j];
#undef STAGE4
}

extern "C" void kernel_launch(void* const* d_in, const int* in_sizes, int n_in,
                              void* d_out, int out_size, void* d_ws, size_t ws_size,
                              hipStream_t stream) {
    const float* x     = (const float*)d_in[0];
    const int*   gi    = (const int*)d_in[1];
    const float* scale = (const float*)d_in[2];
    float* out = (float*)d_out;

    ushort* wbf = (ushort*)d_ws;                          // 32 MB
    ushort* xbf = (ushort*)d_ws + (size_t)OUT_F * IN_F;   // +16 MB

    dequant_w<<<8192, 256, 0, stream>>>(gi, scale, wbf);
    xconv<<<4096, 256, 0, stream>>>(x, xbf);
    gemm8p<<<(M_DIM / 256) * (OUT_F / 256), 512, 0, stream>>>(xbf, wbf, out);
}

// Round 3
// 155.789 us; speedup vs baseline: 1.5724x; 1.0900x over previous
//
#include <hip/hip_runtime.h>
#include <hip/hip_bf16.h>
#include <stdint.h>

typedef __attribute__((ext_vector_type(8))) short short8;
typedef __attribute__((ext_vector_type(4))) float f32x4;
typedef __attribute__((ext_vector_type(4))) float float4v;
typedef __attribute__((ext_vector_type(4))) int int4v;

#define IN_F 2048
#define OUT_F 8192
#define M_DIM 4096        // BATCH * SEQ
#define NT (IN_F / 32)    // 64 K-tiles of BK=32

__device__ __constant__ float c_lut[15] = {
    -1.0f, -0.5f, -0.333333f, -0.2f, -0.142857f, -0.090909f, -0.076923f,
    0.0f, 0.076923f, 0.090909f, 0.142857f, 0.2f, 0.333333f, 0.5f, 1.0f};

// fp32 -> bf16 round-to-nearest-even
__device__ inline ushort f2bf(float f) {
    union { float f; uint32_t u; } v; v.f = f;
    uint32_t u = v.u;
    u += 0x7fffu + ((u >> 16) & 1u);
    return (ushort)(u >> 16);
}

// global -> LDS direct load, 16B per lane; LDS dest linear (base + lane*16).
__device__ inline void gload_lds16(const void* g, void* l) {
    __builtin_amdgcn_global_load_lds(
        (const __attribute__((address_space(1))) void*)(uintptr_t)g,
        (__attribute__((address_space(3))) void*)(uint32_t)(uintptr_t)l,
        16, 0, 0);
}

// ---------------- dequant: grid_indices[int32] -> w_bf16 [OUT_F][IN_F] ----------------
__global__ __launch_bounds__(256) void dequant_w(const int* __restrict__ gi,
                                                 const float* __restrict__ scale_p,
                                                 ushort* __restrict__ w) {
    __shared__ float lut_s[16];
    if (threadIdx.x < 16) {
        float s = scale_p[0];
        lut_s[threadIdx.x] = (threadIdx.x < 15 ? c_lut[threadIdx.x] : 0.0f) * s;
    }
    __syncthreads();
    size_t t = (size_t)blockIdx.x * 256 + threadIdx.x;   // 8 elems per thread
    const int4v* src = (const int4v*)gi;
    int4v v0 = src[t * 2];
    int4v v1 = src[t * 2 + 1];
    short8 o;
    o[0] = (short)f2bf(lut_s[v0.x]);
    o[1] = (short)f2bf(lut_s[v0.y]);
    o[2] = (short)f2bf(lut_s[v0.z]);
    o[3] = (short)f2bf(lut_s[v0.w]);
    o[4] = (short)f2bf(lut_s[v1.x]);
    o[5] = (short)f2bf(lut_s[v1.y]);
    o[6] = (short)f2bf(lut_s[v1.z]);
    o[7] = (short)f2bf(lut_s[v1.w]);
    ((short8*)w)[t] = o;
}

// ---------------- x fp32 -> bf16 [M_DIM][IN_F] ----------------
__global__ __launch_bounds__(256) void xconv(const float* __restrict__ x,
                                             ushort* __restrict__ xb) {
    size_t t = (size_t)blockIdx.x * 256 + threadIdx.x;   // 8 elems per thread
    const float4v* src = (const float4v*)x;
    float4v v0 = src[t * 2];
    float4v v1 = src[t * 2 + 1];
    short8 o;
    o[0] = (short)f2bf(v0.x);
    o[1] = (short)f2bf(v0.y);
    o[2] = (short)f2bf(v0.z);
    o[3] = (short)f2bf(v0.w);
    o[4] = (short)f2bf(v1.x);
    o[5] = (short)f2bf(v1.y);
    o[6] = (short)f2bf(v1.z);
    o[7] = (short)f2bf(v1.w);
    ((short8*)xb)[t] = o;
}

// ---------------- GEMM: C[M][N] = A[M][K] * B[N][K]^T (bf16 in, fp32 out) ----------------
// 256x256 tile, 8 waves (2M x 4N). K-tile = 32, 4-deep LDS ring (4 x 32 KB).
// Per tile: stage t+3 (4 loads/thread), 12 swizzled ds_read_b128, 32 MFMA,
// counted s_waitcnt vmcnt(8) (tiles t+2/t+3 stay in flight), ONE s_barrier.
// Swizzle for 64B rows: 16B-slot' = g ^ ((row>>1)&3); stage source pre-applies
// the inverse so linear global_load_lds realizes it (both-sides rule).
__global__ __launch_bounds__(512, 2) void gemm_ring(const ushort* __restrict__ A,
                                                    const ushort* __restrict__ Bm,
                                                    float* __restrict__ C) {
    __shared__ ushort lds[4][2][256][32];   // [ring][A/B][row][col] = 128 KiB

    const int tid  = threadIdx.x;
    const int lane = tid & 63;
    const int wid  = tid >> 6;
    const int wm = wid >> 2;   // 0..1 : 128-row band
    const int wn = wid & 3;    // 0..3 : 64-col band
    const int g = lane >> 4;   // 0..3 : k-granule
    const int r = lane & 15;

    const int bm = (int)(blockIdx.x & 15) * 256;   // 16 M-tiles fast -> share B panel
    const int bn = (int)(blockIdx.x >> 4) * 256;   // 32 N-tiles

    // Stage addressing: thread covers LDS granule (j*512 + tid) -> row j*128+(tid>>2),
    // 16B-slot' tid&3. Source slot = slot' ^ ((row>>1)&3) = (tid&3)^((tid>>3)&3).
    const int trow  = tid >> 2;                              // 0..127
    const int tcol  = ((tid & 3) ^ ((tid >> 3) & 3)) * 8;    // src col elems
    const ushort* a_base = A  + (size_t)(bm + trow) * IN_F + tcol;
    const ushort* b_base = Bm + (size_t)(bn + trow) * IN_F + tcol;

#define STAGE(t_, reg_)                                                  \
    do {                                                                 \
        const int _ko = (t_) * 32;                                       \
        ushort* _da = &lds[reg_][0][0][0] + tid * 8;                     \
        ushort* _db = &lds[reg_][1][0][0] + tid * 8;                     \
        gload_lds16(a_base + _ko,                        _da);           \
        gload_lds16(a_base + _ko + (size_t)128 * IN_F,   _da + 4096);    \
        gload_lds16(b_base + _ko,                        _db);           \
        gload_lds16(b_base + _ko + (size_t)128 * IN_F,   _db + 4096);    \
    } while (0)

    f32x4 acc[8][4] = {};

    // prologue: stage tiles 0,1,2 into regions 0,1,2; ensure tile 0 landed.
    STAGE(0, 0);
    STAGE(1, 1);
    STAGE(2, 2);
    asm volatile("s_waitcnt vmcnt(8)" ::: "memory");
    __builtin_amdgcn_s_barrier();

#define BODY(tt_, I_)                                                    \
    do {                                                                 \
        const int t = (tt_) + (I_);                                      \
        if (t <= NT - 4) STAGE(t + 3, ((I_) + 3) & 3);                   \
        short8 af[8], bfv[4];                                            \
        const int sl = (g ^ ((r >> 1) & 3)) * 8;                         \
        _Pragma("unroll")                                                \
        for (int f = 0; f < 8; ++f)                                      \
            af[f] = *(const short8*)&lds[I_][0][wm * 128 + f * 16 + r][sl]; \
        _Pragma("unroll")                                                \
        for (int f = 0; f < 4; ++f)                                      \
            bfv[f] = *(const short8*)&lds[I_][1][wn * 64 + f * 16 + r][sl]; \
        __builtin_amdgcn_s_setprio(1);                                   \
        _Pragma("unroll")                                                \
        for (int mi = 0; mi < 8; ++mi)                                   \
            _Pragma("unroll")                                            \
            for (int ni = 0; ni < 4; ++ni)                               \
                acc[mi][ni] = __builtin_amdgcn_mfma_f32_16x16x32_bf16(   \
                    af[mi], bfv[ni], acc[mi][ni], 0, 0, 0);              \
        __builtin_amdgcn_s_setprio(0);                                   \
        if (t <= NT - 4)      { asm volatile("s_waitcnt vmcnt(8)" ::: "memory"); } \
        else if (t == NT - 3) { asm volatile("s_waitcnt vmcnt(4)" ::: "memory"); } \
        else if (t == NT - 2) { asm volatile("s_waitcnt vmcnt(0)" ::: "memory"); } \
        if (t < NT - 1) __builtin_amdgcn_s_barrier();                    \
    } while (0)

    for (int tt = 0; tt < NT; tt += 4) {
        BODY(tt, 0);
        BODY(tt, 1);
        BODY(tt, 2);
        BODY(tt, 3);
    }

    // epilogue: C/D layout col = lane&15, row = (lane>>4)*4 + reg  [verified m89/m91]
    const int crow0 = bm + wm * 128 + g * 4;
    const int ccol0 = bn + wn * 64 + r;
#pragma unroll
    for (int mi = 0; mi < 8; ++mi)
#pragma unroll
        for (int ni = 0; ni < 4; ++ni)
#pragma unroll
            for (int j = 0; j < 4; ++j)
                C[(size_t)(crow0 + mi * 16 + j) * OUT_F + ccol0 + ni * 16] = acc[mi][ni][j];
#undef BODY
#undef STAGE
}

extern "C" void kernel_launch(void* const* d_in, const int* in_sizes, int n_in,
                              void* d_out, int out_size, void* d_ws, size_t ws_size,
                              hipStream_t stream) {
    const float* x     = (const float*)d_in[0];
    const int*   gi    = (const int*)d_in[1];
    const float* scale = (const float*)d_in[2];
    float* out = (float*)d_out;

    ushort* wbf = (ushort*)d_ws;                          // 32 MB
    ushort* xbf = (ushort*)d_ws + (size_t)OUT_F * IN_F;   // +16 MB

    dequant_w<<<8192, 256, 0, stream>>>(gi, scale, wbf);
    xconv<<<4096, 256, 0, stream>>>(x, xbf);
    gemm_ring<<<(M_DIM / 256) * (OUT_F / 256), 512, 0, stream>>>(xbf, wbf, out);
}

// Round 5
// 145.730 us; speedup vs baseline: 1.6810x; 1.0690x over previous
//
#include <hip/hip_runtime.h>
#include <hip/hip_bf16.h>
#include <stdint.h>

typedef __attribute__((ext_vector_type(8))) short short8;
typedef __attribute__((ext_vector_type(4))) float f32x4;
typedef __attribute__((ext_vector_type(4))) float float4v;
typedef __attribute__((ext_vector_type(4))) int int4v;

#define IN_F 2048
#define OUT_F 8192
#define M_DIM 4096        // BATCH * SEQ
#define NT (IN_F / 64)    // 32 K-tiles of BK=64

__device__ __constant__ float c_lut[15] = {
    -1.0f, -0.5f, -0.333333f, -0.2f, -0.142857f, -0.090909f, -0.076923f,
    0.0f, 0.076923f, 0.090909f, 0.142857f, 0.2f, 0.333333f, 0.5f, 1.0f};

__device__ inline ushort f2bf(float f) {
    union { float f; uint32_t u; } v; v.f = f;
    uint32_t u = v.u;
    u += 0x7fffu + ((u >> 16) & 1u);
    return (ushort)(u >> 16);
}

__device__ inline void gload_lds16(const void* g, void* l) {
    __builtin_amdgcn_global_load_lds(
        (const __attribute__((address_space(1))) void*)(uintptr_t)g,
        (__attribute__((address_space(3))) void*)(uint32_t)(uintptr_t)l,
        16, 0, 0);
}

// ---------------- dequant: grid_indices[int32] -> w_bf16 [OUT_F][IN_F] ----------------
__global__ __launch_bounds__(256) void dequant_w(const int* __restrict__ gi,
                                                 const float* __restrict__ scale_p,
                                                 ushort* __restrict__ w) {
    __shared__ float lut_s[16];
    if (threadIdx.x < 16) {
        float s = scale_p[0];
        lut_s[threadIdx.x] = (threadIdx.x < 15 ? c_lut[threadIdx.x] : 0.0f) * s;
    }
    __syncthreads();
    size_t t = (size_t)blockIdx.x * 256 + threadIdx.x;
    const int4v* src = (const int4v*)gi;
    int4v v0 = src[t * 2];
    int4v v1 = src[t * 2 + 1];
    short8 o;
    o[0] = (short)f2bf(lut_s[v0.x]);
    o[1] = (short)f2bf(lut_s[v0.y]);
    o[2] = (short)f2bf(lut_s[v0.z]);
    o[3] = (short)f2bf(lut_s[v0.w]);
    o[4] = (short)f2bf(lut_s[v1.x]);
    o[5] = (short)f2bf(lut_s[v1.y]);
    o[6] = (short)f2bf(lut_s[v1.z]);
    o[7] = (short)f2bf(lut_s[v1.w]);
    ((short8*)w)[t] = o;
}

// ---------------- x fp32 -> bf16 [M_DIM][IN_F] ----------------
__global__ __launch_bounds__(256) void xconv(const float* __restrict__ x,
                                             ushort* __restrict__ xb) {
    size_t t = (size_t)blockIdx.x * 256 + threadIdx.x;
    const float4v* src = (const float4v*)x;
    float4v v0 = src[t * 2];
    float4v v1 = src[t * 2 + 1];
    short8 o;
    o[0] = (short)f2bf(v0.x);
    o[1] = (short)f2bf(v0.y);
    o[2] = (short)f2bf(v0.z);
    o[3] = (short)f2bf(v0.w);
    o[4] = (short)f2bf(v1.x);
    o[5] = (short)f2bf(v1.y);
    o[6] = (short)f2bf(v1.z);
    o[7] = (short)f2bf(v1.w);
    ((short8*)xb)[t] = o;
}

// ---------------- GEMM: C[M][N] = A[M][K] * B[N][K]^T (bf16 in, fp32 out) ----------------
// 256x256 tile, BK=64, 8 waves (2M x 4N), dbuf 128 KiB LDS, 4 phases/K-tile.
// Half-tiles: h1=A-sub0 (first 64 rows of each 128-row wave band),
//             h2=B-sub0 (first 32 rows of each 64-row band), h3=A-sub1, h4=B-sub1.
// Phase p: {pre-barrier ds_read h_p(j) frags; stage h_p(j+1) -> other buf;
//           vmcnt(6); barrier; 16 MFMA (setprio)}.
// vmcnt(6) at phase p retires h_{p+1}(j) (3 newer halves in flight) -> phase
// p+1's pre-barrier reads are guaranteed. Pipeline never drains below 6 in
// steady state; last tile drains 4->2->0. MFMA rotated one phase:
// ph1=Q(1,1) of prev tile, ph2=Q(0,0), ph3=Q(1,0), ph4=Q(0,1).
__global__ __launch_bounds__(512, 2) void gemm4p(const ushort* __restrict__ A,
                                                 const ushort* __restrict__ Bm,
                                                 float* __restrict__ C) {
    __shared__ ushort lds[2][2][256][64];   // [dbuf][A/B][row][col] = 128 KiB

    const int tid  = threadIdx.x;
    const int lane = tid & 63;
    const int wid  = tid >> 6;
    const int wm = wid >> 2;   // 0..1 : 128-row band
    const int wn = wid & 3;    // 0..3 : 64-col band
    const int g = lane >> 4;
    const int r = lane & 15;

    const int bm = (int)(blockIdx.x & 15) * 256;   // M fast -> neighbors share B panel
    const int bn = (int)(blockIdx.x >> 4) * 256;

    // A staging: thread covers rows (tid>>3) + {0,128} (h1) / +{64,192} (h3).
    // Inverse-swizzled source col: ((tid&7) ^ (row&7))*8; row&7 == (tid>>3)&7.
    const int arow = tid >> 3;
    const int acol = ((tid & 7) ^ (arow & 7)) * 8;
    const ushort* a_sbase = A + (size_t)(bm + arow) * IN_F + acol;

    // B staging: wave covers band (wid>>1), 16-row group (wid&1)*16, row lane>>3.
    // brow&7 == lane>>3 -> source col ((lane&7) ^ (lane>>3))*8.
    const int brow0 = (wid >> 1) * 64 + (wid & 1) * 16 + (lane >> 3);
    const int bcol  = ((lane & 7) ^ (lane >> 3)) * 8;
    const ushort* b_sbase = Bm + (size_t)(bn + brow0) * IN_F + bcol;

#define VMCNT6 asm volatile("s_waitcnt vmcnt(6)" ::: "memory")
#define VMCNT4 asm volatile("s_waitcnt vmcnt(4)" ::: "memory")
#define VMCNT2 asm volatile("s_waitcnt vmcnt(2)" ::: "memory")
#define VMCNT0 asm volatile("s_waitcnt vmcnt(0)" ::: "memory")
#define BARRIER()                                                         \
    do {                                                                  \
        asm volatile("" ::: "memory");                                    \
        __builtin_amdgcn_s_barrier();                                     \
        asm volatile("" ::: "memory");                                    \
    } while (0)

// A half q_ (0: rows {0-63,128-191}; 1: {64-127,192-255}) of tile t_ -> buf_
#define STAGE_A(buf_, q_, t_)                                             \
    do {                                                                  \
        const ushort* _s = a_sbase + (size_t)(t_) * 64 + (size_t)(q_) * 64 * IN_F; \
        ushort* _d = &lds[buf_][0][(q_) * 64][0] + tid * 8;               \
        gload_lds16(_s, _d);                                              \
        gload_lds16(_s + (size_t)128 * IN_F, _d + 128 * 64);              \
    } while (0)

// B half q_ (0: first 32 rows of each band; 1: second 32) of tile t_ -> buf_
#define STAGE_B(buf_, q_, t_)                                             \
    do {                                                                  \
        const ushort* _s = b_sbase + (size_t)(t_) * 64 + (size_t)(q_) * 32 * IN_F; \
        ushort* _d = &lds[buf_][1][brow0 + (q_) * 32][0] + (lane & 7) * 8; \
        gload_lds16(_s, _d);                                              \
        gload_lds16(_s + (size_t)8 * IN_F, _d + 8 * 64);                  \
    } while (0)

#define READ_AQ(c_, qa_, dst_)                                            \
    _Pragma("unroll")                                                     \
    for (int f = 0; f < 4; ++f)                                           \
        _Pragma("unroll")                                                 \
        for (int ks = 0; ks < 2; ++ks)                                    \
            dst_[f][ks] = *(const short8*)&lds[c_][0][wm * 128 + (qa_) * 64 + f * 16 + r][((ks * 4 + g) ^ (r & 7)) * 8];

#define READ_BQ(c_, qb_, dst_)                                            \
    _Pragma("unroll")                                                     \
    for (int f = 0; f < 2; ++f)                                           \
        _Pragma("unroll")                                                 \
        for (int ks = 0; ks < 2; ++ks)                                    \
            dst_[f][ks] = *(const short8*)&lds[c_][1][wn * 64 + (qb_) * 32 + f * 16 + r][((ks * 4 + g) ^ (r & 7)) * 8];

#define MFMA_Q(qa_, qb_, asrc_, bsrc_)                                    \
    do {                                                                  \
        __builtin_amdgcn_s_setprio(1);                                    \
        _Pragma("unroll")                                                 \
        for (int f = 0; f < 4; ++f)                                       \
            _Pragma("unroll")                                             \
            for (int f2 = 0; f2 < 2; ++f2)                                \
                _Pragma("unroll")                                         \
                for (int ks = 0; ks < 2; ++ks)                            \
                    acc[(qa_) * 4 + f][(qb_) * 2 + f2] =                  \
                        __builtin_amdgcn_mfma_f32_16x16x32_bf16(          \
                            asrc_[f][ks], bsrc_[f2][ks],                  \
                            acc[(qa_) * 4 + f][(qb_) * 2 + f2], 0, 0, 0); \
        __builtin_amdgcn_s_setprio(0);                                    \
    } while (0)

#define TILE_STEADY(c_, t_, P1_)                                          \
    do {                                                                  \
        READ_AQ(c_, 0, aq0);                                              \
        STAGE_A((c_) ^ 1, 0, (t_) + 1);                                   \
        VMCNT6; BARRIER();                                                \
        if (P1_) MFMA_Q(1, 1, aq1, bq1);                                  \
        READ_BQ(c_, 0, bq0);                                              \
        STAGE_B((c_) ^ 1, 0, (t_) + 1);                                   \
        VMCNT6; BARRIER();                                                \
        MFMA_Q(0, 0, aq0, bq0);                                           \
        READ_AQ(c_, 1, aq1);                                              \
        STAGE_A((c_) ^ 1, 1, (t_) + 1);                                   \
        VMCNT6; BARRIER();                                                \
        MFMA_Q(1, 0, aq1, bq0);                                           \
        READ_BQ(c_, 1, bq1);                                              \
        STAGE_B((c_) ^ 1, 1, (t_) + 1);                                   \
        VMCNT6; BARRIER();                                                \
        MFMA_Q(0, 1, aq0, bq1);                                           \
    } while (0)

#define TILE_LAST(c_)                                                     \
    do {                                                                  \
        READ_AQ(c_, 0, aq0);                                              \
        VMCNT4; BARRIER();                                                \
        MFMA_Q(1, 1, aq1, bq1);                                           \
        READ_BQ(c_, 0, bq0);                                              \
        VMCNT2; BARRIER();                                                \
        MFMA_Q(0, 0, aq0, bq0);                                           \
        READ_AQ(c_, 1, aq1);                                              \
        VMCNT0; BARRIER();                                                \
        MFMA_Q(1, 0, aq1, bq0);                                           \
        READ_BQ(c_, 1, bq1);                                              \
        MFMA_Q(0, 1, aq0, bq1);                                           \
    } while (0)

    f32x4 acc[8][4] = {};
    short8 aq0[4][2], aq1[4][2], bq0[2][2], bq1[2][2];

    // prologue: stage tile 0 (h1..h4, 8 loads); retire h1 before first read.
    STAGE_A(0, 0, 0);
    STAGE_B(0, 0, 0);
    STAGE_A(0, 1, 0);
    STAGE_B(0, 1, 0);
    VMCNT6;
    BARRIER();

    TILE_STEADY(0, 0, 0);                 // tile 0: no prev-tile MFMA at ph1
    for (int tt = 1; tt < NT - 1; tt += 2) {
        TILE_STEADY(1, tt, 1);            // tiles 1..30 (last stages tile 31)
        TILE_STEADY(0, tt + 1, 1);
    }
    TILE_LAST(1);                          // tile 31, drain 4->2->0
    MFMA_Q(1, 1, aq1, bq1);                // deferred last quadrant of tile 31

    // epilogue: C/D layout col = lane&15, row = (lane>>4)*4 + reg  [verified m89/m91]
    const int crow0 = bm + wm * 128 + g * 4;
    const int ccol0 = bn + wn * 64 + r;
#pragma unroll
    for (int mi = 0; mi < 8; ++mi)
#pragma unroll
        for (int ni = 0; ni < 4; ++ni)
#pragma unroll
            for (int j = 0; j < 4; ++j)
                C[(size_t)(crow0 + mi * 16 + j) * OUT_F + ccol0 + ni * 16] = acc[mi][ni][j];

#undef TILE_LAST
#undef TILE_STEADY
#undef MFMA_Q
#undef READ_BQ
#undef READ_AQ
#undef STAGE_B
#undef STAGE_A
#undef BARRIER
#undef VMCNT0
#undef VMCNT2
#undef VMCNT4
#undef VMCNT6
}

extern "C" void kernel_launch(void* const* d_in, const int* in_sizes, int n_in,
                              void* d_out, int out_size, void* d_ws, size_t ws_size,
                              hipStream_t stream) {
    const float* x     = (const float*)d_in[0];
    const int*   gi    = (const int*)d_in[1];
    const float* scale = (const float*)d_in[2];
    float* out = (float*)d_out;

    ushort* wbf = (ushort*)d_ws;                          // 32 MB
    ushort* xbf = (ushort*)d_ws + (size_t)OUT_F * IN_F;   // +16 MB

    dequant_w<<<8192, 256, 0, stream>>>(gi, scale, wbf);
    xconv<<<4096, 256, 0, stream>>>(x, xbf);
    gemm4p<<<(M_DIM / 256) * (OUT_F / 256), 512, 0, stream>>>(xbf, wbf, out);
}